// Round 6
// baseline (175.781 us; speedup 1.0000x reference)
//
#include <hip/hip_runtime.h>
#include <hip/hip_bf16.h>
#include <math.h>

// Problem constants
#define NB 8      // batch
#define NC 128    // channels
#define NH 64     // height
#define NW 64     // width
#define NP 1024   // npatch (32x32)
#define TWO_SIG2 5.12f      // 2*(0.05*32)^2
#define LOG2E 1.44269504089f

// ws layout (bytes):
//   psum : [NB][3][4cc][NP] fp32            = 384 KB  (partial exp row-sums)
//   pbuf : [NB*NP][3ch][4 part][3] fp32     = 1.18 MB (top-3 partials)
//   cnt  : [NB*16] int                      = 512 B   (last-block counters)
//   xd   : [NB*2][NP][NC] bf16              = 4 MB
static const size_t PSUM_OFF_B = 0;
static const size_t PBUF_OFF_B = (size_t)NB * 3 * 4 * NP * 4;
static const size_t CNT_OFF_B  = PBUF_OFF_B + (size_t)NB * NP * 3 * 4 * 3 * 4;
static const size_t XD_OFF_B   = CNT_OFF_B + 1024;

typedef __bf16 bf16x8 __attribute__((ext_vector_type(8)));
typedef float f32x4 __attribute__((ext_vector_type(4)));

__device__ __forceinline__ int iabs_(int v) { return v < 0 ? -v : v; }

// Insert v into sorted-descending triple (A >= B >= C): 3 instrs via med3
#define INSERT3(v, A, Bq, Cq)                          \
  {                                                    \
    const float _na = fmaxf(A, (v));                   \
    const float _nb = __builtin_amdgcn_fmed3f(A, Bq, (v)); \
    Cq = __builtin_amdgcn_fmed3f(Bq, Cq, (v));         \
    A = _na;                                           \
    Bq = _nb;                                          \
  }

// Merge two sorted-descending triples (a <- top3 of union)
#define MERGE3(a0, a1, a2, b0, b1, b2)       \
  {                                          \
    const float _x1 = fmaxf(a0, b0);         \
    const float _y1 = fminf(a0, b0);         \
    const float _x2 = fmaxf(a1, b1);         \
    const float _z  = fmaxf(a2, b2);         \
    a0 = _x1;                                \
    a1 = fmaxf(_y1, _x2);                    \
    a2 = fmaxf(fminf(_y1, _x2), _z);         \
  }

// ---------------------------------------------------------------------------
// K1: L2-normalize over channels at the two diagonal pixels of each 2x2 patch
//     and write transposed xd[b][p][n][c] (c contiguous) as bf16.
// grid (16 chunks of 64 patches, p=2, b=8), block 256
// ---------------------------------------------------------------------------
__global__ __launch_bounds__(256) void k1_norm(const float* __restrict__ x,
                                               __hip_bfloat16* __restrict__ xd) {
  __shared__ __align__(16) float tile[NC * 65];
  const int chunk = blockIdx.x;
  const int p = blockIdx.y;
  const int b = blockIdx.z;
  const int t = threadIdx.x;
  const int pix = t & 63;
  const int cw = t >> 6;
  const int nbase = chunk * 64;

  {
    const int n = nbase + pix;
    const int i = ((n >> 5) << 1) + p;   // 2r + p
    const int jf = (n & 31);             // float2 index: cols (2jf, 2jf+1)
    const float* xb = x + (size_t)b * NC * NH * NW + (size_t)i * NW;
    for (int cc = 0; cc < 32; ++cc) {
      const int c = (cc << 2) + cw;
      const float2 v2 = ((const float2*)(xb + (size_t)c * NH * NW))[jf];
      tile[c * 65 + pix] = (p == 0) ? v2.x : v2.y;
    }
  }
  __syncthreads();

  const int lane = t & 63;
  const int w = t >> 6;
  for (int pg = 0; pg < 16; ++pg) {
    const int pixel = (pg << 2) + w;     // each wave owns one pixel (128 channels)
    const float v0 = tile[lane * 65 + pixel];
    const float v1 = tile[(lane + 64) * 65 + pixel];
    float ss = v0 * v0 + v1 * v1;
#pragma unroll
    for (int m = 32; m >= 1; m >>= 1) ss += __shfl_xor(ss, m, 64);
    const float inv = 1.0f / fmaxf(sqrtf(ss), 1e-12f);
    __hip_bfloat16* xr = xd + ((size_t)((b * 2 + p) * NP) + nbase + pixel) * NC;
    xr[lane] = __float2bfloat16(v0 * inv);
    xr[lane + 64] = __float2bfloat16(v1 * inv);
  }
}

// ---------------------------------------------------------------------------
// K2: fused corr (MFMA, registers) -> mask -> exp2 -> PARTIAL row sums.
// No atomics: block (cchunk,rowtile,b) writes psum[b][ch][cchunk][n].
// Also zeroes the K4 last-block counters (kernel-boundary ordering).
// grid (4 colchunk, 16 rowtile, 8 b), block 256 (4 waves; wave owns 16 rows)
// ---------------------------------------------------------------------------
__global__ __launch_bounds__(256) void k2_sums(const ushort* __restrict__ xd,
                                               const float* __restrict__ alpha_p,
                                               float* __restrict__ psum,
                                               int* __restrict__ cnt) {
  __shared__ __align__(16) __bf16 As[2][64 * 136];
  __shared__ __align__(16) __bf16 Bs[2][64 * 136];
  __shared__ float er[32];    // gaussian table
  __shared__ float erA[32];   // alpha*log2e * er
  const int t = threadIdx.x;
  const float K = (*alpha_p) * LOG2E;
  if (t < 32) {
    const float e = __expf(-(float)(t * t) / TWO_SIG2);
    er[t] = e;
    erA[t] = K * e;
  }

  const int cchunk = blockIdx.x;
  const int rowtile = blockIdx.y;
  const int b = blockIdx.z;
  const int i0 = rowtile << 6;
  const int jb = cchunk << 8;

  if (cchunk == 0 && t == 0) cnt[b * 16 + rowtile] = 0;  // reset K4 counters

#pragma unroll
  for (int pl = 0; pl < 2; ++pl) {
    const float4* ga = (const float4*)(xd + ((size_t)(b * 2 + pl) * NP + i0) * NC);
#pragma unroll
    for (int it = 0; it < 4; ++it) {
      const int f = (it << 8) + t;
      const int r = f >> 4, q = f & 15;
      *(float4*)(&As[pl][r * 136 + q * 8]) = ga[f];
    }
  }

  const int wave = t >> 6;
  const int lane = t & 63;
  const int lrow = lane & 15;
  const int kq = lane >> 4;

  float sums[3][4];
#pragma unroll
  for (int ch = 0; ch < 3; ++ch)
#pragma unroll
    for (int reg = 0; reg < 4; ++reg) sums[ch][reg] = 0.f;

  for (int sc = 0; sc < 4; ++sc) {
    const int j0 = jb + (sc << 6);
    __syncthreads();
#pragma unroll
    for (int pl = 0; pl < 2; ++pl) {
      const float4* gb = (const float4*)(xd + ((size_t)(b * 2 + pl) * NP + j0) * NC);
#pragma unroll
      for (int it = 0; it < 4; ++it) {
        const int f = (it << 8) + t;
        const int r = f >> 4, q = f & 15;
        *(float4*)(&Bs[pl][r * 136 + q * 8]) = gb[f];
      }
    }
    __syncthreads();

    f32x4 acc[2][4];
#pragma unroll
    for (int pl = 0; pl < 2; ++pl)
#pragma unroll
      for (int ct = 0; ct < 4; ++ct)
#pragma unroll
        for (int u = 0; u < 4; ++u) acc[pl][ct][u] = 0.f;

#pragma unroll
    for (int kc = 0; kc < 4; ++kc) {
      const int kk = kc * 32 + (kq << 3);
      const bf16x8 a0 = *(const bf16x8*)(&As[0][(wave * 16 + lrow) * 136 + kk]);
      const bf16x8 a1 = *(const bf16x8*)(&As[1][(wave * 16 + lrow) * 136 + kk]);
#pragma unroll
      for (int ct = 0; ct < 4; ++ct) {
        const bf16x8 b0 = *(const bf16x8*)(&Bs[0][(ct * 16 + lrow) * 136 + kk]);
        const bf16x8 b1 = *(const bf16x8*)(&Bs[1][(ct * 16 + lrow) * 136 + kk]);
        acc[0][ct] = __builtin_amdgcn_mfma_f32_16x16x32_bf16(a0, b0, acc[0][ct], 0, 0, 0);
        acc[1][ct] = __builtin_amdgcn_mfma_f32_16x16x32_bf16(a1, b1, acc[1][ct], 0, 0, 0);
      }
    }

    // mask + exp2 + accumulate partial row sums
#pragma unroll
    for (int ct = 0; ct < 4; ++ct) {
      const int m = j0 + ct * 16 + lrow;
      const int rm = m >> 5, cm = m & 31;
#pragma unroll
      for (int reg = 0; reg < 4; ++reg) {
        const int n = i0 + wave * 16 + kq * 4 + reg;
        const int rn = n >> 5, cn = n & 31;
        // fm2 = log2e*alpha*(1-g); exact 0 on the diagonal
        const float fm2 = fmaf(-erA[iabs_(rn - rm)], er[iabs_(cn - cm)], K);
        const float g0 = fm2 * acc[0][ct][reg];
        const float g1 = fm2 * acc[1][ct][reg];
        sums[0][reg] += exp2f(g0);
        sums[1][reg] += exp2f(g1);
        sums[2][reg] += exp2f(0.5f * (g0 + g1));
      }
    }
  }

  // reduce across the 16 col-lanes (same rows)
#pragma unroll
  for (int off = 1; off < 16; off <<= 1)
#pragma unroll
    for (int ch = 0; ch < 3; ++ch)
#pragma unroll
      for (int reg = 0; reg < 4; ++reg)
        sums[ch][reg] += __shfl_xor(sums[ch][reg], off, 64);

  if (lrow == 0) {
#pragma unroll
    for (int ch = 0; ch < 3; ++ch)
#pragma unroll
      for (int reg = 0; reg < 4; ++reg) {
        const int n = i0 + wave * 16 + kq * 4 + reg;
        psum[(((size_t)b * 3 + ch) * 4 + cchunk) * NP + n] = sums[ch][reg];
      }
  }
}

// ---------------------------------------------------------------------------
// K4: fused corr recompute -> mask -> exp2 -> q = E^2 * ir_m -> online top-3
// per row per channel; writes per-colchunk partials; LAST block of each
// (b,rowtile) group merges the 4 partials and scatters to out.
// grid (4 colchunk, 16 rowtile, 8 b), block 256
// ---------------------------------------------------------------------------
__global__ __launch_bounds__(256) void k4_topk(const ushort* __restrict__ xd,
                                               const float* __restrict__ alpha_p,
                                               const float* __restrict__ psum,
                                               float* __restrict__ pbuf,
                                               int* __restrict__ cnt,
                                               float* __restrict__ out) {
  __shared__ __align__(16) __bf16 As[2][64 * 136];
  __shared__ __align__(16) __bf16 Bs[2][64 * 136];
  __shared__ float er[32];
  __shared__ float erA[32];
  __shared__ float rsr[3][64];    // 1/rowsum over this block's rows
  __shared__ float rsc[3][256];   // 1/rowsum over this block's cols
  __shared__ int lastFlag;
  const int t = threadIdx.x;
  const float K = (*alpha_p) * LOG2E;
  if (t < 32) {
    const float e = __expf(-(float)(t * t) / TWO_SIG2);
    er[t] = e;
    erA[t] = K * e;
  }

  const int cchunk = blockIdx.x;
  const int rowtile = blockIdx.y;
  const int b = blockIdx.z;
  const int i0 = rowtile << 6;
  const int jb = cchunk << 8;

  if (t < 192) {
    const int ch = t >> 6, r = t & 63;
    const float* pp = psum + ((size_t)b * 3 + ch) * 4 * NP + i0 + r;
    rsr[ch][r] = 1.0f / (pp[0] + pp[NP] + pp[2 * NP] + pp[3 * NP]);
  }
#pragma unroll
  for (int ch = 0; ch < 3; ++ch) {
    const float* pp = psum + ((size_t)b * 3 + ch) * 4 * NP + jb + t;
    rsc[ch][t] = 1.0f / (pp[0] + pp[NP] + pp[2 * NP] + pp[3 * NP]);
  }

#pragma unroll
  for (int pl = 0; pl < 2; ++pl) {
    const float4* ga = (const float4*)(xd + ((size_t)(b * 2 + pl) * NP + i0) * NC);
#pragma unroll
    for (int it = 0; it < 4; ++it) {
      const int f = (it << 8) + t;
      const int r = f >> 4, q = f & 15;
      *(float4*)(&As[pl][r * 136 + q * 8]) = ga[f];
    }
  }

  const int wave = t >> 6;
  const int lane = t & 63;
  const int lrow = lane & 15;
  const int kq = lane >> 4;

  float tA[3][4], tB[3][4], tC[3][4];
#pragma unroll
  for (int ch = 0; ch < 3; ++ch)
#pragma unroll
    for (int reg = 0; reg < 4; ++reg) { tA[ch][reg] = 0.f; tB[ch][reg] = 0.f; tC[ch][reg] = 0.f; }

  for (int sc = 0; sc < 4; ++sc) {
    const int j0 = jb + (sc << 6);
    __syncthreads();
#pragma unroll
    for (int pl = 0; pl < 2; ++pl) {
      const float4* gb = (const float4*)(xd + ((size_t)(b * 2 + pl) * NP + j0) * NC);
#pragma unroll
      for (int it = 0; it < 4; ++it) {
        const int f = (it << 8) + t;
        const int r = f >> 4, q = f & 15;
        *(float4*)(&Bs[pl][r * 136 + q * 8]) = gb[f];
      }
    }
    __syncthreads();

    f32x4 acc[2][4];
#pragma unroll
    for (int pl = 0; pl < 2; ++pl)
#pragma unroll
      for (int ct = 0; ct < 4; ++ct)
#pragma unroll
        for (int u = 0; u < 4; ++u) acc[pl][ct][u] = 0.f;

#pragma unroll
    for (int kc = 0; kc < 4; ++kc) {
      const int kk = kc * 32 + (kq << 3);
      const bf16x8 a0 = *(const bf16x8*)(&As[0][(wave * 16 + lrow) * 136 + kk]);
      const bf16x8 a1 = *(const bf16x8*)(&As[1][(wave * 16 + lrow) * 136 + kk]);
#pragma unroll
      for (int ct = 0; ct < 4; ++ct) {
        const bf16x8 b0 = *(const bf16x8*)(&Bs[0][(ct * 16 + lrow) * 136 + kk]);
        const bf16x8 b1 = *(const bf16x8*)(&Bs[1][(ct * 16 + lrow) * 136 + kk]);
        acc[0][ct] = __builtin_amdgcn_mfma_f32_16x16x32_bf16(a0, b0, acc[0][ct], 0, 0, 0);
        acc[1][ct] = __builtin_amdgcn_mfma_f32_16x16x32_bf16(a1, b1, acc[1][ct], 0, 0, 0);
      }
    }

#pragma unroll
    for (int ct = 0; ct < 4; ++ct) {
      const int mc = sc * 64 + ct * 16 + lrow;   // col index within chunk (0..255)
      const int m = jb + mc;
      const int rm = m >> 5, cm = m & 31;
      const float im0 = rsc[0][mc], im1 = rsc[1][mc], im2 = rsc[2][mc];
#pragma unroll
      for (int reg = 0; reg < 4; ++reg) {
        const int nr = wave * 16 + kq * 4 + reg;  // row within tile (0..63)
        const int n = i0 + nr;
        const int rn = n >> 5, cn = n & 31;
        const float fm2 = fmaf(-erA[iabs_(rn - rm)], er[iabs_(cn - cm)], K);
        const float g0 = fm2 * acc[0][ct][reg];
        const float g1 = fm2 * acc[1][ct][reg];
        const float e0 = exp2f(g0);
        const float e1 = exp2f(g1);
        const float q0 = e0 * e0 * im0;   // ir_n folded in at the end
        const float q1 = e1 * e1 * im1;
        const float q2 = e0 * e1 * im2;   // e2^2 == e0*e1 (one fewer exp2)
        INSERT3(q0, tA[0][reg], tB[0][reg], tC[0][reg]);
        INSERT3(q1, tA[1][reg], tB[1][reg], tC[1][reg]);
        INSERT3(q2, tA[2][reg], tB[2][reg], tC[2][reg]);
      }
    }
  }

  // merge across the 16 col-lanes (they hold the same rows)
#pragma unroll
  for (int off = 1; off < 16; off <<= 1)
#pragma unroll
    for (int ch = 0; ch < 3; ++ch)
#pragma unroll
      for (int reg = 0; reg < 4; ++reg) {
        const float b0 = __shfl_xor(tA[ch][reg], off, 64);
        const float b1 = __shfl_xor(tB[ch][reg], off, 64);
        const float b2 = __shfl_xor(tC[ch][reg], off, 64);
        MERGE3(tA[ch][reg], tB[ch][reg], tC[ch][reg], b0, b1, b2);
      }

  if (lrow == 0) {
#pragma unroll
    for (int ch = 0; ch < 3; ++ch)
#pragma unroll
      for (int reg = 0; reg < 4; ++reg) {
        const int nr = wave * 16 + kq * 4 + reg;
        const int n = i0 + nr;
        const float irn = rsr[ch][nr];
        const size_t base = ((((size_t)b * NP + n) * 3 + ch) * 4 + cchunk) * 3;
        pbuf[base + 0] = tA[ch][reg] * irn;
        pbuf[base + 1] = tB[ch][reg] * irn;
        pbuf[base + 2] = tC[ch][reg] * irn;
      }
  }

  // -------- last-block merge + scatter (replaces the old K5 kernel) --------
  __threadfence();           // release our pbuf writes to device scope
  __syncthreads();
  if (t == 0) lastFlag = (atomicAdd(&cnt[b * 16 + rowtile], 1) == 3);
  __syncthreads();
  if (!lastFlag) return;
  __threadfence();           // acquire: see the other 3 blocks' pbuf writes

  if (t < 192) {
    const int r = t & 63;            // row within tile
    const int ch = t >> 6;           // channel 0..2
    const int n = i0 + r;
    const size_t base = (((size_t)b * NP + n) * 3 + ch) * 4 * 3;
    float f0 = pbuf[base + 0], f1 = pbuf[base + 1], f2 = pbuf[base + 2];
#pragma unroll
    for (int p = 1; p < 4; ++p) {
      const float b0 = pbuf[base + p * 3 + 0];
      const float b1 = pbuf[base + p * 3 + 1];
      const float b2 = pbuf[base + p * 3 + 2];
      MERGE3(f0, f1, f2, b0, b1, b2);
    }

    // scatter: ch 0 -> (2r,2c); 1 -> (2r+1,2c+1); 2 -> (2r,2c+1)+(2r+1,2c)
    const int rn = n >> 5, cn = n & 31;
    float* ob = out + (size_t)b * 3 * (NH * NW);
    const int i00 = ((rn << 1) * NW) + (cn << 1);
    const float v[3] = {f0, f1, f2};
#pragma unroll
    for (int tt = 0; tt < 3; ++tt) {
      float* op = ob + (size_t)tt * (NH * NW);
      if (ch == 0) {
        op[i00] = v[tt];
      } else if (ch == 1) {
        op[i00 + NW + 1] = v[tt];
      } else {
        op[i00 + 1] = v[tt];
        op[i00 + NW] = v[tt];
      }
    }
  }
}

extern "C" void kernel_launch(void* const* d_in, const int* in_sizes, int n_in,
                              void* d_out, int out_size, void* d_ws, size_t ws_size,
                              hipStream_t stream) {
  const float* x = (const float*)d_in[0];
  const float* alpha = (const float*)d_in[1];
  float* out = (float*)d_out;
  char* ws = (char*)d_ws;

  float* psum = (float*)(ws + PSUM_OFF_B);
  float* pbuf = (float*)(ws + PBUF_OFF_B);
  int* cnt = (int*)(ws + CNT_OFF_B);
  __hip_bfloat16* xd = (__hip_bfloat16*)(ws + XD_OFF_B);

  k1_norm<<<dim3(16, 2, NB), 256, 0, stream>>>(x, xd);
  k2_sums<<<dim3(4, 16, NB), 256, 0, stream>>>((const ushort*)xd, alpha, psum, cnt);
  k4_topk<<<dim3(4, 16, NB), 256, 0, stream>>>((const ushort*)xd, alpha, psum, pbuf, cnt, out);
}

// Round 7
// 110.414 us; speedup vs baseline: 1.5920x; 1.5920x over previous
//
#include <hip/hip_runtime.h>
#include <hip/hip_bf16.h>
#include <math.h>

// Problem constants
#define NB 8      // batch
#define NC 128    // channels
#define NH 64     // height
#define NW 64     // width
#define NP 1024   // npatch (32x32)
#define TWO_SIG2 5.12f      // 2*(0.05*32)^2
#define LOG2E 1.44269504089f

// ws layout (bytes):
//   psum : [NB][3][4cc][NP] fp32            = 384 KB  (partial exp row-sums)
//   pbuf : [NB*NP][3ch][4 part][3] fp32     = 1.18 MB (top-3 partials)
//   xd   : [NB*2][NP][NC] bf16              = 4 MB
static const size_t PSUM_OFF_B = 0;
static const size_t PBUF_OFF_B = (size_t)NB * 3 * 4 * NP * 4;
static const size_t XD_OFF_B   = PBUF_OFF_B + (size_t)NB * NP * 3 * 4 * 3 * 4;

typedef __bf16 bf16x8 __attribute__((ext_vector_type(8)));
typedef float f32x4 __attribute__((ext_vector_type(4)));

__device__ __forceinline__ int iabs_(int v) { return v < 0 ? -v : v; }

// Insert v into sorted-descending triple (A >= B >= C): 3 instrs via med3
#define INSERT3(v, A, Bq, Cq)                          \
  {                                                    \
    const float _na = fmaxf(A, (v));                   \
    const float _nb = __builtin_amdgcn_fmed3f(A, Bq, (v)); \
    Cq = __builtin_amdgcn_fmed3f(Bq, Cq, (v));         \
    A = _na;                                           \
    Bq = _nb;                                          \
  }

// Merge two sorted-descending triples (a <- top3 of union)
#define MERGE3(a0, a1, a2, b0, b1, b2)       \
  {                                          \
    const float _x1 = fmaxf(a0, b0);         \
    const float _y1 = fminf(a0, b0);         \
    const float _x2 = fmaxf(a1, b1);         \
    const float _z  = fmaxf(a2, b2);         \
    a0 = _x1;                                \
    a1 = fmaxf(_y1, _x2);                    \
    a2 = fmaxf(fminf(_y1, _x2), _z);         \
  }

// ---------------------------------------------------------------------------
// K1: L2-normalize over channels at the two diagonal pixels of each 2x2 patch
//     and write transposed xd[b][p][n][c] (c contiguous) as bf16.
// grid (16 chunks of 64 patches, p=2, b=8), block 256
// ---------------------------------------------------------------------------
__global__ __launch_bounds__(256) void k1_norm(const float* __restrict__ x,
                                               __hip_bfloat16* __restrict__ xd) {
  __shared__ __align__(16) float tile[NC * 65];
  const int chunk = blockIdx.x;
  const int p = blockIdx.y;
  const int b = blockIdx.z;
  const int t = threadIdx.x;
  const int pix = t & 63;
  const int cw = t >> 6;
  const int nbase = chunk * 64;

  {
    const int n = nbase + pix;
    const int i = ((n >> 5) << 1) + p;   // 2r + p
    const int jf = (n & 31);             // float2 index: cols (2jf, 2jf+1)
    const float* xb = x + (size_t)b * NC * NH * NW + (size_t)i * NW;
    for (int cc = 0; cc < 32; ++cc) {
      const int c = (cc << 2) + cw;
      const float2 v2 = ((const float2*)(xb + (size_t)c * NH * NW))[jf];
      tile[c * 65 + pix] = (p == 0) ? v2.x : v2.y;
    }
  }
  __syncthreads();

  const int lane = t & 63;
  const int w = t >> 6;
  for (int pg = 0; pg < 16; ++pg) {
    const int pixel = (pg << 2) + w;     // each wave owns one pixel (128 channels)
    const float v0 = tile[lane * 65 + pixel];
    const float v1 = tile[(lane + 64) * 65 + pixel];
    float ss = v0 * v0 + v1 * v1;
#pragma unroll
    for (int m = 32; m >= 1; m >>= 1) ss += __shfl_xor(ss, m, 64);
    const float inv = 1.0f / fmaxf(sqrtf(ss), 1e-12f);
    __hip_bfloat16* xr = xd + ((size_t)((b * 2 + p) * NP) + nbase + pixel) * NC;
    xr[lane] = __float2bfloat16(v0 * inv);
    xr[lane + 64] = __float2bfloat16(v1 * inv);
  }
}

// ---------------------------------------------------------------------------
// K2: fused corr (MFMA, registers) -> mask -> exp2 -> PARTIAL row sums.
// No atomics: block (cchunk,rowtile,b) writes psum[b][ch][cchunk][n].
// grid (4 colchunk, 16 rowtile, 8 b), block 256 (4 waves; wave owns 16 rows)
// ---------------------------------------------------------------------------
__global__ __launch_bounds__(256) void k2_sums(const ushort* __restrict__ xd,
                                               const float* __restrict__ alpha_p,
                                               float* __restrict__ psum) {
  __shared__ __align__(16) __bf16 As[2][64 * 136];
  __shared__ __align__(16) __bf16 Bs[2][64 * 136];
  __shared__ float er[32];    // gaussian table
  __shared__ float erA[32];   // alpha*log2e * er
  const int t = threadIdx.x;
  const float K = (*alpha_p) * LOG2E;
  if (t < 32) {
    const float e = __expf(-(float)(t * t) / TWO_SIG2);
    er[t] = e;
    erA[t] = K * e;
  }

  const int cchunk = blockIdx.x;
  const int rowtile = blockIdx.y;
  const int b = blockIdx.z;
  const int i0 = rowtile << 6;
  const int jb = cchunk << 8;

#pragma unroll
  for (int pl = 0; pl < 2; ++pl) {
    const float4* ga = (const float4*)(xd + ((size_t)(b * 2 + pl) * NP + i0) * NC);
#pragma unroll
    for (int it = 0; it < 4; ++it) {
      const int f = (it << 8) + t;
      const int r = f >> 4, q = f & 15;
      *(float4*)(&As[pl][r * 136 + q * 8]) = ga[f];
    }
  }

  const int wave = t >> 6;
  const int lane = t & 63;
  const int lrow = lane & 15;
  const int kq = lane >> 4;

  float sums[3][4];
#pragma unroll
  for (int ch = 0; ch < 3; ++ch)
#pragma unroll
    for (int reg = 0; reg < 4; ++reg) sums[ch][reg] = 0.f;

  for (int sc = 0; sc < 4; ++sc) {
    const int j0 = jb + (sc << 6);
    __syncthreads();
#pragma unroll
    for (int pl = 0; pl < 2; ++pl) {
      const float4* gb = (const float4*)(xd + ((size_t)(b * 2 + pl) * NP + j0) * NC);
#pragma unroll
      for (int it = 0; it < 4; ++it) {
        const int f = (it << 8) + t;
        const int r = f >> 4, q = f & 15;
        *(float4*)(&Bs[pl][r * 136 + q * 8]) = gb[f];
      }
    }
    __syncthreads();

    f32x4 acc[2][4];
#pragma unroll
    for (int pl = 0; pl < 2; ++pl)
#pragma unroll
      for (int ct = 0; ct < 4; ++ct)
#pragma unroll
        for (int u = 0; u < 4; ++u) acc[pl][ct][u] = 0.f;

#pragma unroll
    for (int kc = 0; kc < 4; ++kc) {
      const int kk = kc * 32 + (kq << 3);
      const bf16x8 a0 = *(const bf16x8*)(&As[0][(wave * 16 + lrow) * 136 + kk]);
      const bf16x8 a1 = *(const bf16x8*)(&As[1][(wave * 16 + lrow) * 136 + kk]);
#pragma unroll
      for (int ct = 0; ct < 4; ++ct) {
        const bf16x8 b0 = *(const bf16x8*)(&Bs[0][(ct * 16 + lrow) * 136 + kk]);
        const bf16x8 b1 = *(const bf16x8*)(&Bs[1][(ct * 16 + lrow) * 136 + kk]);
        acc[0][ct] = __builtin_amdgcn_mfma_f32_16x16x32_bf16(a0, b0, acc[0][ct], 0, 0, 0);
        acc[1][ct] = __builtin_amdgcn_mfma_f32_16x16x32_bf16(a1, b1, acc[1][ct], 0, 0, 0);
      }
    }

    // mask + exp2 + accumulate partial row sums
#pragma unroll
    for (int ct = 0; ct < 4; ++ct) {
      const int m = j0 + ct * 16 + lrow;
      const int rm = m >> 5, cm = m & 31;
#pragma unroll
      for (int reg = 0; reg < 4; ++reg) {
        const int n = i0 + wave * 16 + kq * 4 + reg;
        const int rn = n >> 5, cn = n & 31;
        // fm2 = log2e*alpha*(1-g); exact 0 on the diagonal
        const float fm2 = fmaf(-erA[iabs_(rn - rm)], er[iabs_(cn - cm)], K);
        const float g0 = fm2 * acc[0][ct][reg];
        const float g1 = fm2 * acc[1][ct][reg];
        sums[0][reg] += exp2f(g0);
        sums[1][reg] += exp2f(g1);
        sums[2][reg] += exp2f(0.5f * (g0 + g1));
      }
    }
  }

  // reduce across the 16 col-lanes (same rows)
#pragma unroll
  for (int off = 1; off < 16; off <<= 1)
#pragma unroll
    for (int ch = 0; ch < 3; ++ch)
#pragma unroll
      for (int reg = 0; reg < 4; ++reg)
        sums[ch][reg] += __shfl_xor(sums[ch][reg], off, 64);

  if (lrow == 0) {
#pragma unroll
    for (int ch = 0; ch < 3; ++ch)
#pragma unroll
      for (int reg = 0; reg < 4; ++reg) {
        const int n = i0 + wave * 16 + kq * 4 + reg;
        psum[(((size_t)b * 3 + ch) * 4 + cchunk) * NP + n] = sums[ch][reg];
      }
  }
}

// ---------------------------------------------------------------------------
// K4: fused corr recompute -> mask -> exp2 -> q = E^2 * ir_m -> online top-3
// per row per channel (ir_n applied to the winners at the end).
// grid (4 colchunk, 16 rowtile, 8 b), block 256
// ---------------------------------------------------------------------------
__global__ __launch_bounds__(256) void k4_topk(const ushort* __restrict__ xd,
                                               const float* __restrict__ alpha_p,
                                               const float* __restrict__ psum,
                                               float* __restrict__ pbuf) {
  __shared__ __align__(16) __bf16 As[2][64 * 136];
  __shared__ __align__(16) __bf16 Bs[2][64 * 136];
  __shared__ float er[32];
  __shared__ float erA[32];
  __shared__ float rsr[3][64];    // 1/rowsum over this block's rows
  __shared__ float rsc[3][256];   // 1/rowsum over this block's cols
  const int t = threadIdx.x;
  const float K = (*alpha_p) * LOG2E;
  if (t < 32) {
    const float e = __expf(-(float)(t * t) / TWO_SIG2);
    er[t] = e;
    erA[t] = K * e;
  }

  const int cchunk = blockIdx.x;
  const int rowtile = blockIdx.y;
  const int b = blockIdx.z;
  const int i0 = rowtile << 6;
  const int jb = cchunk << 8;

  if (t < 192) {
    const int ch = t >> 6, r = t & 63;
    const float* pp = psum + ((size_t)b * 3 + ch) * 4 * NP + i0 + r;
    rsr[ch][r] = 1.0f / (pp[0] + pp[NP] + pp[2 * NP] + pp[3 * NP]);
  }
#pragma unroll
  for (int ch = 0; ch < 3; ++ch) {
    const float* pp = psum + ((size_t)b * 3 + ch) * 4 * NP + jb + t;
    rsc[ch][t] = 1.0f / (pp[0] + pp[NP] + pp[2 * NP] + pp[3 * NP]);
  }

#pragma unroll
  for (int pl = 0; pl < 2; ++pl) {
    const float4* ga = (const float4*)(xd + ((size_t)(b * 2 + pl) * NP + i0) * NC);
#pragma unroll
    for (int it = 0; it < 4; ++it) {
      const int f = (it << 8) + t;
      const int r = f >> 4, q = f & 15;
      *(float4*)(&As[pl][r * 136 + q * 8]) = ga[f];
    }
  }

  const int wave = t >> 6;
  const int lane = t & 63;
  const int lrow = lane & 15;
  const int kq = lane >> 4;

  float tA[3][4], tB[3][4], tC[3][4];
#pragma unroll
  for (int ch = 0; ch < 3; ++ch)
#pragma unroll
    for (int reg = 0; reg < 4; ++reg) { tA[ch][reg] = 0.f; tB[ch][reg] = 0.f; tC[ch][reg] = 0.f; }

  for (int sc = 0; sc < 4; ++sc) {
    const int j0 = jb + (sc << 6);
    __syncthreads();
#pragma unroll
    for (int pl = 0; pl < 2; ++pl) {
      const float4* gb = (const float4*)(xd + ((size_t)(b * 2 + pl) * NP + j0) * NC);
#pragma unroll
      for (int it = 0; it < 4; ++it) {
        const int f = (it << 8) + t;
        const int r = f >> 4, q = f & 15;
        *(float4*)(&Bs[pl][r * 136 + q * 8]) = gb[f];
      }
    }
    __syncthreads();

    f32x4 acc[2][4];
#pragma unroll
    for (int pl = 0; pl < 2; ++pl)
#pragma unroll
      for (int ct = 0; ct < 4; ++ct)
#pragma unroll
        for (int u = 0; u < 4; ++u) acc[pl][ct][u] = 0.f;

#pragma unroll
    for (int kc = 0; kc < 4; ++kc) {
      const int kk = kc * 32 + (kq << 3);
      const bf16x8 a0 = *(const bf16x8*)(&As[0][(wave * 16 + lrow) * 136 + kk]);
      const bf16x8 a1 = *(const bf16x8*)(&As[1][(wave * 16 + lrow) * 136 + kk]);
#pragma unroll
      for (int ct = 0; ct < 4; ++ct) {
        const bf16x8 b0 = *(const bf16x8*)(&Bs[0][(ct * 16 + lrow) * 136 + kk]);
        const bf16x8 b1 = *(const bf16x8*)(&Bs[1][(ct * 16 + lrow) * 136 + kk]);
        acc[0][ct] = __builtin_amdgcn_mfma_f32_16x16x32_bf16(a0, b0, acc[0][ct], 0, 0, 0);
        acc[1][ct] = __builtin_amdgcn_mfma_f32_16x16x32_bf16(a1, b1, acc[1][ct], 0, 0, 0);
      }
    }

#pragma unroll
    for (int ct = 0; ct < 4; ++ct) {
      const int mc = sc * 64 + ct * 16 + lrow;   // col index within chunk (0..255)
      const int m = jb + mc;
      const int rm = m >> 5, cm = m & 31;
      const float im0 = rsc[0][mc], im1 = rsc[1][mc], im2 = rsc[2][mc];
#pragma unroll
      for (int reg = 0; reg < 4; ++reg) {
        const int nr = wave * 16 + kq * 4 + reg;  // row within tile (0..63)
        const int n = i0 + nr;
        const int rn = n >> 5, cn = n & 31;
        const float fm2 = fmaf(-erA[iabs_(rn - rm)], er[iabs_(cn - cm)], K);
        const float g0 = fm2 * acc[0][ct][reg];
        const float g1 = fm2 * acc[1][ct][reg];
        const float e0 = exp2f(g0);
        const float e1 = exp2f(g1);
        const float q0 = e0 * e0 * im0;   // ir_n folded in at the end
        const float q1 = e1 * e1 * im1;
        const float q2 = e0 * e1 * im2;   // e2^2 == exp2(g0+g1) == e0*e1
        INSERT3(q0, tA[0][reg], tB[0][reg], tC[0][reg]);
        INSERT3(q1, tA[1][reg], tB[1][reg], tC[1][reg]);
        INSERT3(q2, tA[2][reg], tB[2][reg], tC[2][reg]);
      }
    }
  }

  // merge across the 16 col-lanes (they hold the same rows)
#pragma unroll
  for (int off = 1; off < 16; off <<= 1)
#pragma unroll
    for (int ch = 0; ch < 3; ++ch)
#pragma unroll
      for (int reg = 0; reg < 4; ++reg) {
        const float b0 = __shfl_xor(tA[ch][reg], off, 64);
        const float b1 = __shfl_xor(tB[ch][reg], off, 64);
        const float b2 = __shfl_xor(tC[ch][reg], off, 64);
        MERGE3(tA[ch][reg], tB[ch][reg], tC[ch][reg], b0, b1, b2);
      }

  if (lrow == 0) {
#pragma unroll
    for (int ch = 0; ch < 3; ++ch)
#pragma unroll
      for (int reg = 0; reg < 4; ++reg) {
        const int nr = wave * 16 + kq * 4 + reg;
        const int n = i0 + nr;
        const float irn = rsr[ch][nr];
        const size_t base = ((((size_t)b * NP + n) * 3 + ch) * 4 + cchunk) * 3;
        pbuf[base + 0] = tA[ch][reg] * irn;
        pbuf[base + 1] = tB[ch][reg] * irn;
        pbuf[base + 2] = tC[ch][reg] * irn;
      }
  }
}

// ---------------------------------------------------------------------------
// K5: merge the 4 per-colchunk top-3 partials and scatter to output.
// grid (32), block 256 — one thread per (b, n).
// ---------------------------------------------------------------------------
__global__ __launch_bounds__(256) void k5_merge(const float* __restrict__ pbuf,
                                                float* __restrict__ out) {
  const int tau = blockIdx.x * 256 + threadIdx.x;   // 0..8191
  const int b = tau >> 10;
  const int n = tau & (NP - 1);
  const int rn = n >> 5, cn = n & 31;

  float f0[3], f1[3], f2[3];
#pragma unroll
  for (int ch = 0; ch < 3; ++ch) {
    const size_t base = (((size_t)tau * 3 + ch) * 4) * 3;
    f0[ch] = pbuf[base + 0];
    f1[ch] = pbuf[base + 1];
    f2[ch] = pbuf[base + 2];
#pragma unroll
    for (int p = 1; p < 4; ++p) {
      const float b0 = pbuf[base + p * 3 + 0];
      const float b1 = pbuf[base + p * 3 + 1];
      const float b2 = pbuf[base + p * 3 + 2];
      MERGE3(f0[ch], f1[ch], f2[ch], b0, b1, b2);
    }
  }

  // scatter: channel 0 -> (2r,2c); 1 -> (2r+1,2c+1); 2 -> (2r,2c+1) and (2r+1,2c)
  float* ob = out + (size_t)b * 3 * (NH * NW);
  const int i00 = ((rn << 1) * NW) + (cn << 1);
#pragma unroll
  for (int tt = 0; tt < 3; ++tt) {
    float* op = ob + (size_t)tt * (NH * NW);
    const float r0 = (tt == 0) ? f0[0] : (tt == 1) ? f1[0] : f2[0];
    const float r1 = (tt == 0) ? f0[1] : (tt == 1) ? f1[1] : f2[1];
    const float r2 = (tt == 0) ? f0[2] : (tt == 1) ? f1[2] : f2[2];
    op[i00] = r0;            // (2r, 2c)
    op[i00 + NW + 1] = r1;   // (2r+1, 2c+1)
    op[i00 + 1] = r2;        // (2r, 2c+1)
    op[i00 + NW] = r2;       // (2r+1, 2c)
  }
}

extern "C" void kernel_launch(void* const* d_in, const int* in_sizes, int n_in,
                              void* d_out, int out_size, void* d_ws, size_t ws_size,
                              hipStream_t stream) {
  const float* x = (const float*)d_in[0];
  const float* alpha = (const float*)d_in[1];
  float* out = (float*)d_out;
  char* ws = (char*)d_ws;

  float* psum = (float*)(ws + PSUM_OFF_B);
  float* pbuf = (float*)(ws + PBUF_OFF_B);
  __hip_bfloat16* xd = (__hip_bfloat16*)(ws + XD_OFF_B);

  k1_norm<<<dim3(16, 2, NB), 256, 0, stream>>>(x, xd);
  k2_sums<<<dim3(4, 16, NB), 256, 0, stream>>>((const ushort*)xd, alpha, psum);
  k4_topk<<<dim3(4, 16, NB), 256, 0, stream>>>((const ushort*)xd, alpha, psum, pbuf);
  k5_merge<<<dim3(32), 256, 0, stream>>>(pbuf, out);
}